// Round 6
// baseline (181.799 us; speedup 1.0000x reference)
//
#include <hip/hip_runtime.h>
#include <hip/hip_bf16.h>

typedef __attribute__((ext_vector_type(8))) short short8;
typedef __attribute__((ext_vector_type(4))) float f32x4;

#define NT 65536

__device__ __forceinline__ unsigned short f2bf(float f) {
    union { float f; unsigned int u; } v; v.f = f;
    unsigned int u = v.u;
    unsigned int r = (u + 0x7fffu + ((u >> 16) & 1u)) >> 16;  // RNE
    return (unsigned short)r;
}

__device__ __forceinline__ unsigned int cvt_pk_bf16(float lo, float hi) {
    unsigned int r;
    asm("v_cvt_pk_bf16_f32 %0, %1, %2" : "=v"(r) : "v"(lo), "v"(hi));
    return r;
}

#define LGKM0() asm volatile("s_waitcnt lgkmcnt(0)" ::: "memory")
#define VMC0()  asm volatile("s_waitcnt vmcnt(0)" ::: "memory")
#define BAR()   __builtin_amdgcn_s_barrier()
#define SB0()   __builtin_amdgcn_sched_barrier(0)

// ---------------- prep (all 3 sources): bf16 B panel + per-k params ----------------
// Panel row n: k16=n>>5, typ=(n>>4)&1, r=n&15 -> k=k16*16+r; typ0=w, typ1=beta.
// prm per source (5*256 f32): [0:256)=||w_k||^2, [256)=gam^2, [512)=eta^2, [768)=alpha, [1024)=sig^2
__global__ void prep_kernel(const float* __restrict__ w0, const float* __restrict__ b0,
                            const float* __restrict__ a0, const float* __restrict__ s0,
                            const float* __restrict__ e0, const float* __restrict__ g0,
                            const float* __restrict__ w1, const float* __restrict__ b1,
                            const float* __restrict__ a1, const float* __restrict__ s1,
                            const float* __restrict__ e1, const float* __restrict__ g1,
                            const float* __restrict__ w2, const float* __restrict__ b2,
                            const float* __restrict__ a2, const float* __restrict__ s2,
                            const float* __restrict__ e2, const float* __restrict__ g2,
                            unsigned short* __restrict__ bc, float* __restrict__ prmAll) {
    __shared__ float red[2];
    const int bx = blockIdx.x;
    const int s = bx >> 9;            // 0..2
    const int n = bx & 511;           // panel row
    const int P = 512 >> s;
    const float* w   = (s == 0) ? w0 : ((s == 1) ? w1 : w2);
    const float* bet = (s == 0) ? b0 : ((s == 1) ? b1 : b2);
    const float* alp = (s == 0) ? a0 : ((s == 1) ? a1 : a2);
    const float* sig = (s == 0) ? s0 : ((s == 1) ? s1 : s2);
    const float* eta = (s == 0) ? e0 : ((s == 1) ? e1 : e2);
    const float* gam = (s == 0) ? g0 : ((s == 1) ? g1 : g2);
    unsigned short* dstb = bc + ((s == 0) ? 0 : ((s == 1) ? (512 * 512) : (512 * 512 + 512 * 256)));
    float* prm = prmAll + 1280 * s;

    const int tid = threadIdx.x;      // 128
    const int k16 = n >> 5;
    const int typ = (n >> 4) & 1;
    const int k = k16 * 16 + (n & 15);
    const bool isw = (typ == 0);
    const float* src = (isw ? w : bet) + (size_t)k * P;
    unsigned short* dst = dstb + (size_t)n * P;
    float ss = 0.f;
    for (int c = tid; c < P; c += 128) {
        float f = src[c];
        dst[c] = f2bf(f);
        if (isw) ss += f * f;
    }
#pragma unroll
    for (int m = 1; m < 64; m <<= 1) ss += __shfl_xor(ss, m);
    if ((tid & 63) == 0) red[tid >> 6] = ss;
    __syncthreads();
    if (isw && tid == 0) prm[k] = red[0] + red[1];
    if (n == 0) {
        for (int kk = tid; kk < 256; kk += 128) {
            float g = gam[kk], e = eta[kk];
            prm[256 + kk]  = g * g;
            prm[512 + kk]  = e * e;
            prm[768 + kk]  = alp[kk];
            prm[1024 + kk] = sig[kk] * sig[kk];
        }
    }
}

// ---------------- fused (all sources): 256x256-tile GEMM + RBF epilogue ----------------
// grid 1536, 512 thr (8 waves, 2(wr) x 4(wcn)). bx>>9 = source; local = bx&511:
// mt = local&255 (M-tile of 256 rows), h = local>>8 (N-half: panel cols [256h,256h+256)).
// Siblings (h0,h1 for same mt) are 256 apart -> same XCD -> L2/L3 dedup of x.
// K-loop: NK = P/64 steps of BK=64. B staged via global_load_lds (XOR-swizzled source,
// linear LDS); A reg-staged (T14): fp32 loads for t+1 issued BEFORE compute(t),
// cvt+ds_write AFTER compute(t). Raw s_barrier + lgkmcnt(0) only (no vmcnt(0) drain
// in steady state; the cvt's register waits retire older gload_lds first - counted-vmcnt
// semantics with issue order pinned by sched_barrier(0)).
// A LDS rows padded to 72 ushorts (144B) -> bank-period broken, write & read conflict-free.
__global__ __launch_bounds__(512, 2)
void fused_all(const float* __restrict__ x0, const float* __restrict__ x1, const float* __restrict__ x2,
               const unsigned short* __restrict__ bcAll, const float* __restrict__ prmAll,
               float* __restrict__ pws) {
    __shared__ unsigned short Ab[2][256 * 72];   // 72 KB
    __shared__ unsigned short Bb[2][256 * 64];   // 64 KB
    __shared__ float xn2[256];
    __shared__ float part[4][256][3];

    const int bx = blockIdx.x;
    const int s  = bx >> 9;
    const int local = bx & 511;
    const int mt = local & 255;
    const int h  = local >> 8;
    const int P  = 512 >> s;
    const int NK = P >> 6;
    const float* x = (s == 0) ? x0 : ((s == 1) ? x1 : x2);
    const unsigned short* Bc = bcAll + ((s == 0) ? 0 : ((s == 1) ? (512 * 512) : (512 * 512 + 512 * 256)));
    const float* prm = prmAll + 1280 * s;
    float* pw = pws + (size_t)(s * 6 + h * 3) * NT;
    const int row0 = mt * 256;

    const int tid = threadIdx.x, lane = tid & 63, wv = tid >> 6;
    const int wr = wv >> 2, wcn = wv & 3;
    const int l15 = lane & 15, l4 = lane >> 4;

    // A staging: thread -> row = tid>>1 (0..255), 32-col half = tid&1
    const int arow = tid >> 1, ahalf = tid & 1;
    const float* xrow = x + (size_t)(row0 + arow) * P + ahalf * 32;

    // B staging (global_load_lds, 4 ops): unit u = i*512+tid; row = i*64 + (tid>>3);
    // phys slot = tid&7; logical slot = phys ^ (row&7) = (tid&7) ^ ((tid>>3)&7)
    const int brr = tid >> 3;
    const int bslot = (tid & 7) ^ (brr & 7);

    f32x4 acc[8][4];
#pragma unroll
    for (int rf = 0; rf < 8; rf++)
#pragma unroll
        for (int cf = 0; cf < 4; cf++) acc[rf][cf] = (f32x4){0.f, 0.f, 0.f, 0.f};

    float ss = 0.f;
    float4 ar[8];

    auto stage_B = [&](int nb, int t) {
#pragma unroll
        for (int i = 0; i < 4; i++) {
            const unsigned short* src = Bc + (size_t)(256 * h + i * 64 + brr) * P + t * 64 + bslot * 8;
            __builtin_amdgcn_global_load_lds((const __attribute__((address_space(1))) void*)src,
                                             (__attribute__((address_space(3))) void*)&Bb[nb][(i * 512 + wv * 64) * 8],
                                             16, 0, 0);
        }
    };
    auto load_A = [&](int t) {
#pragma unroll
        for (int i = 0; i < 8; i++) ar[i] = *(const float4*)(xrow + t * 64 + i * 4);
    };
    auto cvt_write_A = [&](int nb) {
#pragma unroll
        for (int i2 = 0; i2 < 4; i2++) {
            float4 q0 = ar[2 * i2], q1 = ar[2 * i2 + 1];
            ss += q0.x*q0.x + q0.y*q0.y + q0.z*q0.z + q0.w*q0.w
                + q1.x*q1.x + q1.y*q1.y + q1.z*q1.z + q1.w*q1.w;
            uint4 pk = { cvt_pk_bf16(q0.x, q0.y), cvt_pk_bf16(q0.z, q0.w),
                         cvt_pk_bf16(q1.x, q1.y), cvt_pk_bf16(q1.z, q1.w) };
            *(uint4*)(&Ab[nb][arow * 72 + (ahalf * 4 + i2) * 8]) = pk;
        }
    };
    auto compute = [&](int buf) {
#pragma unroll
        for (int kk = 0; kk < 2; kk++) {
            short8 bfr[4];
#pragma unroll
            for (int cf = 0; cf < 4; cf++) {
                const int rowb = wcn * 64 + cf * 16 + l15;
                bfr[cf] = *(const short8*)(&Bb[buf][rowb * 64 + (((kk * 4 + l4) ^ (rowb & 7)) << 3)]);
            }
#pragma unroll
            for (int rf = 0; rf < 8; rf++) {
                const int rowa = wr * 128 + rf * 16 + l15;
                short8 af = *(const short8*)(&Ab[buf][rowa * 72 + (kk * 4 + l4) * 8]);
#pragma unroll
                for (int cf = 0; cf < 4; cf++)
                    acc[rf][cf] = __builtin_amdgcn_mfma_f32_16x16x32_bf16(af, bfr[cf], acc[rf][cf], 0, 0, 0);
            }
        }
    };

    // ---- prologue: tile 0 ----
    stage_B(0, 0);
    SB0();
    load_A(0);
    SB0();
    cvt_write_A(0);
    VMC0(); LGKM0(); BAR(); SB0();

    // ---- main loop ----
#pragma unroll 1
    for (int t = 0; t < NK - 1; t++) {
        const int buf = t & 1;
        stage_B(buf ^ 1, t + 1);
        SB0();
        load_A(t + 1);
        SB0();
        compute(buf);
        SB0();
        cvt_write_A(buf ^ 1);   // reg-dep waits retire older gload_lds too
        LGKM0(); BAR(); SB0();
    }
    compute((NK - 1) & 1);
    VMC0(); LGKM0(); BAR(); SB0();

    // ---- ||x||^2 finalize ----
    ss += __shfl_xor(ss, 1);
    if (ahalf == 0) xn2[arow] = ss;
    __syncthreads();

    // ---- epilogue: lane holds x-row = wr*128+rf*16+l4*4+j, panel-col = 256h+wcn*64+cf*16+l15
    // cf = 2q+typ: q -> k16 = 8h+2wcn+q, k = k16*16+l15; typ0=w-dot, typ1=beta-dot
    float wn2q[2], g2q[2], hvq[2], alq[2], s2q[2];
#pragma unroll
    for (int q = 0; q < 2; q++) {
        const int k = (8 * h + 2 * wcn + q) * 16 + l15;
        wn2q[q] = prm[k];
        g2q[q]  = prm[256 + k];
        hvq[q]  = prm[512 + k];
        alq[q]  = prm[768 + k];
        s2q[q]  = prm[1024 + k];
    }
#pragma unroll
    for (int rf = 0; rf < 8; rf++) {
#pragma unroll
        for (int j = 0; j < 4; j++) {
            const int row = wr * 128 + rf * 16 + l4 * 4 + j;
            const float xv = xn2[row];
            float hs = 0.f, ms = 0.f, gs = 0.f;
#pragma unroll
            for (int q = 0; q < 2; q++) {
                const float aw = acc[rf][2 * q][j];
                const float ab2 = acc[rf][2 * q + 1][j];
                const float d2 = xv - 2.f * aw + wn2q[q];
                const float a  = __expf(-g2q[q] * d2);
                const float ah = a * hvq[q];
                hs += ah;
                ms += (ab2 + alq[q]) * ah;
                gs += s2q[q] * ah * ah;
            }
#pragma unroll
            for (int msk = 1; msk < 16; msk <<= 1) {
                hs += __shfl_xor(hs, msk);
                ms += __shfl_xor(ms, msk);
                gs += __shfl_xor(gs, msk);
            }
            if (l15 == 0) {
                part[wcn][row][0] = hs;
                part[wcn][row][1] = ms;
                part[wcn][row][2] = gs;
            }
        }
    }
    __syncthreads();
    if (tid < 256) {
#pragma unroll
        for (int v = 0; v < 3; v++) {
            float sum = part[0][tid][v] + part[1][tid][v] + part[2][tid][v] + part[3][tid][v];
            pw[(size_t)v * NT + row0 + tid] = sum;
        }
    }
}

// ---------------- combine: all outputs from partials ----------------
__global__ void combine_kernel(const float* __restrict__ pws,
                               const float* __restrict__ d0, const float* __restrict__ d1,
                               const float* __restrict__ d2, float* __restrict__ out) {
    const int t = blockIdx.x * 256 + threadIdx.x;
    float mux[3], s2x[3], hx[3];
#pragma unroll
    for (int s = 0; s < 3; s++) {
        const float* b = pws + (size_t)s * 6 * NT;
        const float hh = b[t] + b[(size_t)3 * NT + t];
        const float mm = b[(size_t)1 * NT + t] + b[(size_t)4 * NT + t];
        const float gg = b[(size_t)2 * NT + t] + b[(size_t)5 * NT + t];
        mux[s] = mm / hh; s2x[s] = gg / (hh * hh); hx[s] = hh;
        out[(size_t)s * NT + t]       = mux[s];
        out[(size_t)(4 + s) * NT + t] = s2x[s];
        out[(size_t)(8 + s) * NT + t] = hh;
    }
    const float sd0 = 1.f / (1.f + __expf(-d0[0]));
    const float sd1 = 1.f / (1.f + __expf(-d1[0]));
    const float sd2 = 1.f / (1.f + __expf(-d2[0]));
    const float c0 = hx[0] * sd0, c1 = hx[1] * sd1, c2 = hx[2] * sd2;
    const float den = c0 + c1 + c2;
    const float muc = mux[0] * c0 + mux[1] * c1 + mux[2] * c2;
    const float sgc = s2x[0] * c0 * c0 + s2x[1] * c1 * c1 + s2x[2] * c2 * c2;
    out[(size_t)3 * NT + t]  = muc / den;
    out[(size_t)7 * NT + t]  = sgc / (den * den);
    out[(size_t)11 * NT + t] = den;
}

extern "C" void kernel_launch(void* const* d_in, const int* in_sizes, int n_in,
                              void* d_out, int out_size, void* d_ws, size_t ws_size,
                              hipStream_t stream) {
    // input order per source i: x=8i, alpha=8i+1, beta=8i+2, sig=8i+3, eta=8i+4, gam=8i+5, w=8i+6, disc=8i+7
    const float* x0 = (const float*)d_in[0];
    const float* x1 = (const float*)d_in[8];
    const float* x2 = (const float*)d_in[16];

    unsigned short* bc = (unsigned short*)d_ws;                  // 512*(512+256+128) ushorts = 917504 B
    float* prmAll = (float*)((char*)d_ws + 917504);              // 3*1280 floats = 15360 B
    float* pws    = (float*)((char*)d_ws + 917504 + 15360);      // 18*NT floats = 4.72 MB
    float* out = (float*)d_out;

    prep_kernel<<<1536, 128, 0, stream>>>(
        (const float*)d_in[6],  (const float*)d_in[2],  (const float*)d_in[1],
        (const float*)d_in[3],  (const float*)d_in[4],  (const float*)d_in[5],
        (const float*)d_in[14], (const float*)d_in[10], (const float*)d_in[9],
        (const float*)d_in[11], (const float*)d_in[12], (const float*)d_in[13],
        (const float*)d_in[22], (const float*)d_in[18], (const float*)d_in[17],
        (const float*)d_in[19], (const float*)d_in[20], (const float*)d_in[21],
        bc, prmAll);
    fused_all<<<1536, 512, 0, stream>>>(x0, x1, x2, bc, prmAll, pws);
    combine_kernel<<<256, 256, 0, stream>>>(pws, (const float*)d_in[7], (const float*)d_in[15],
                                            (const float*)d_in[23], out);
}

// Round 7
// 130.351 us; speedup vs baseline: 1.3947x; 1.3947x over previous
//
#include <hip/hip_runtime.h>
#include <hip/hip_bf16.h>

typedef __attribute__((ext_vector_type(8))) short short8;
typedef __attribute__((ext_vector_type(4))) float f32x4;

#define NT 65536

__device__ __forceinline__ unsigned short f2bf(float f) {
    union { float f; unsigned int u; } v; v.f = f;
    unsigned int u = v.u;
    unsigned int r = (u + 0x7fffu + ((u >> 16) & 1u)) >> 16;  // RNE
    return (unsigned short)r;
}

__device__ __forceinline__ unsigned int cvt_pk_bf16(float lo, float hi) {
    unsigned int r;
    asm("v_cvt_pk_bf16_f32 %0, %1, %2" : "=v"(r) : "v"(lo), "v"(hi));
    return r;
}

#define LGKM0()  asm volatile("s_waitcnt lgkmcnt(0)" ::: "memory")
#define VMCNT6() asm volatile("s_waitcnt vmcnt(6)" ::: "memory")
#define VMCNT0() asm volatile("s_waitcnt vmcnt(0)" ::: "memory")
#define BAR()    __builtin_amdgcn_s_barrier()
#define SB0()    __builtin_amdgcn_sched_barrier(0)

// ---------------- prep (all 3 sources): bf16 B panel + per-k params ----------------
// Panel row n: k16=n>>5, typ=(n>>4)&1, r=n&15 -> k=k16*16+r; typ0=w, typ1=beta.
// prm per source (5*256 f32): [0:256)=||w_k||^2, [256)=gam^2, [512)=eta^2, [768)=alpha, [1024)=sig^2
__global__ void prep_kernel(const float* __restrict__ w0, const float* __restrict__ b0,
                            const float* __restrict__ a0, const float* __restrict__ s0,
                            const float* __restrict__ e0, const float* __restrict__ g0,
                            const float* __restrict__ w1, const float* __restrict__ b1,
                            const float* __restrict__ a1, const float* __restrict__ s1,
                            const float* __restrict__ e1, const float* __restrict__ g1,
                            const float* __restrict__ w2, const float* __restrict__ b2,
                            const float* __restrict__ a2, const float* __restrict__ s2,
                            const float* __restrict__ e2, const float* __restrict__ g2,
                            unsigned short* __restrict__ bc, float* __restrict__ prmAll) {
    __shared__ float red[2];
    const int bx = blockIdx.x;
    const int s = bx >> 9;            // 0..2
    const int n = bx & 511;           // panel row
    const int P = 512 >> s;
    const float* w   = (s == 0) ? w0 : ((s == 1) ? w1 : w2);
    const float* bet = (s == 0) ? b0 : ((s == 1) ? b1 : b2);
    const float* alp = (s == 0) ? a0 : ((s == 1) ? a1 : a2);
    const float* sig = (s == 0) ? s0 : ((s == 1) ? s1 : s2);
    const float* eta = (s == 0) ? e0 : ((s == 1) ? e1 : e2);
    const float* gam = (s == 0) ? g0 : ((s == 1) ? g1 : g2);
    unsigned short* dstb = bc + ((s == 0) ? 0 : ((s == 1) ? (512 * 512) : (512 * 512 + 512 * 256)));
    float* prm = prmAll + 1280 * s;

    const int tid = threadIdx.x;      // 128
    const int k16 = n >> 5;
    const int typ = (n >> 4) & 1;
    const int k = k16 * 16 + (n & 15);
    const bool isw = (typ == 0);
    const float* src = (isw ? w : bet) + (size_t)k * P;
    unsigned short* dst = dstb + (size_t)n * P;
    float ss = 0.f;
    for (int c = tid; c < P; c += 128) {
        float f = src[c];
        dst[c] = f2bf(f);
        if (isw) ss += f * f;
    }
#pragma unroll
    for (int m = 1; m < 64; m <<= 1) ss += __shfl_xor(ss, m);
    if ((tid & 63) == 0) red[tid >> 6] = ss;
    __syncthreads();
    if (isw && tid == 0) prm[k] = red[0] + red[1];
    if (n == 0) {
        for (int kk = tid; kk < 256; kk += 128) {
            float g = gam[kk], e = eta[kk];
            prm[256 + kk]  = g * g;
            prm[512 + kk]  = e * e;
            prm[768 + kk]  = alp[kk];
            prm[1024 + kk] = sig[kk] * sig[kk];
        }
    }
}

// ---------------- fused per-source: small-tile streaming GEMM + RBF epilogue ----------------
// grid 2048, 256 thr (4 waves 2(panel)x2(x)). Block: 128 panel-rows (pt) x 128 x-rows (xt),
// BK=32, NK=P/32. Swizzled grid: b -> xt=(b>>5)*8+(b&7), pt=(b>>3)&3 so the 4 pt-siblings
// of one x-tile land on ONE XCD (bx%8 fixed) -> L2/L3 dedup of x.
// Swapped MFMA: mfma(panel_frag, x_frag) -> lane holds panel-row (k) in regs, x-row = l15.
// Epilogue k-reduction: register adds + 2 shuffles (k is lane-local).
// Pipeline: 1-step lookahead; B via global_load_lds (pre-swizzled source), x reg-staged
// (static ping-pong xra/xrb); counted vmcnt(6) - never 0 in steady state; 2 barriers/step.
// LDS 16B-slot swizzle: phys = slot ^ ((row>>1)&3) -> 2-way max on all reads (free).
template<int P>
__global__ __launch_bounds__(256, 3)
void fused_src(const float* __restrict__ x, const unsigned short* __restrict__ Bc,
               const float* __restrict__ prm, float* __restrict__ pwsS) {
    constexpr int NK = P / 32;
    __shared__ unsigned short Bs[2][128 * 32];   // 16 KB
    __shared__ unsigned short Xs[128 * 32];      // 8 KB, aliased as part[2][128][3] at end
    __shared__ float xn2[128];

    const int b = blockIdx.x;
    const int xt = (b >> 5) * 8 + (b & 7);
    const int pt = (b >> 3) & 3;

    const int tid = threadIdx.x, lane = tid & 63, wv = tid >> 6;
    const int wp = wv >> 1, wx = wv & 1;
    const int l15 = lane & 15, l4 = lane >> 4;

    const int srow = tid >> 1, shalf = tid & 1;
    const float* xbase = x + (size_t)(xt * 128 + srow) * P + shalf * 16;

    f32x4 acc[4][4];
#pragma unroll
    for (int pf = 0; pf < 4; pf++)
#pragma unroll
        for (int xf = 0; xf < 4; xf++) acc[pf][xf] = (f32x4){0.f, 0.f, 0.f, 0.f};

    float4 xra[4], xrb[4];
    float ss = 0.f;

    auto gloadB = [&](int nb, int t) {
#pragma unroll
        for (int i = 0; i < 2; i++) {
            const int u = i * 256 + tid;
            const int row = u >> 2;
            const int sl = (u & 3) ^ ((row >> 1) & 3);
            const unsigned short* src = Bc + (size_t)(pt * 128 + row) * P + t * 32 + sl * 8;
            __builtin_amdgcn_global_load_lds((const __attribute__((address_space(1))) void*)src,
                (__attribute__((address_space(3))) void*)&Bs[nb][(i * 256 + wv * 64) * 8], 16, 0, 0);
        }
    };
    auto loadX = [&](float4* xr, int t) {
#pragma unroll
        for (int i = 0; i < 4; i++) xr[i] = *(const float4*)(xbase + t * 32 + i * 4);
    };
    auto cvtWrite = [&](const float4* xr) {
        const int sw = (srow >> 1) & 3;
#pragma unroll
        for (int hh = 0; hh < 2; hh++) {
            float4 q0 = xr[2 * hh], q1 = xr[2 * hh + 1];
            ss += q0.x*q0.x + q0.y*q0.y + q0.z*q0.z + q0.w*q0.w
                + q1.x*q1.x + q1.y*q1.y + q1.z*q1.z + q1.w*q1.w;
            uint4 pk = { cvt_pk_bf16(q0.x, q0.y), cvt_pk_bf16(q0.z, q0.w),
                         cvt_pk_bf16(q1.x, q1.y), cvt_pk_bf16(q1.z, q1.w) };
            const int phys = (shalf * 2 + hh) ^ sw;
            *(uint4*)(&Xs[srow * 32 + phys * 8]) = pk;
        }
    };
    auto compute = [&](int buf) {
        short8 af[4], bf[4];
#pragma unroll
        for (int pf = 0; pf < 4; pf++) {
            const int row = 64 * wp + 16 * pf + l15;
            af[pf] = *(const short8*)(&Bs[buf][row * 32 + ((l4 ^ ((row >> 1) & 3)) << 3)]);
        }
#pragma unroll
        for (int xf = 0; xf < 4; xf++) {
            const int row = 64 * wx + 16 * xf + l15;
            bf[xf] = *(const short8*)(&Xs[row * 32 + ((l4 ^ ((row >> 1) & 3)) << 3)]);
        }
#pragma unroll
        for (int pf = 0; pf < 4; pf++)
#pragma unroll
            for (int xf = 0; xf < 4; xf++)
                acc[pf][xf] = __builtin_amdgcn_mfma_f32_16x16x32_bf16(af[pf], bf[xf], acc[pf][xf], 0, 0, 0);
    };

    // ---- prologue ----
    gloadB(0, 0);
    loadX(xra, 0);

    // ---- main loop: 2 steps per trip (static reg ping-pong) ----
#pragma unroll 1
    for (int t = 0; t < NK; t += 2) {
        // even step t (always has a successor since NK is even)
        gloadB((t + 1) & 1, t + 1);
        loadX(xrb, t + 1);
        cvtWrite(xra);
        VMCNT6(); LGKM0(); SB0(); BAR(); SB0();
        compute(t & 1);
        SB0(); BAR(); SB0();
        // odd step t+1
        const bool more = (t + 2 < NK);
        if (more) {
            gloadB(t & 1, t + 2);
            loadX(xra, t + 2);
        }
        cvtWrite(xrb);
        if (more) { VMCNT6(); } else { VMCNT0(); }
        LGKM0(); SB0(); BAR(); SB0();
        compute((t + 1) & 1);
        SB0(); BAR(); SB0();
    }

    // ---- ||x||^2 finalize (2 threads per row) ----
    ss += __shfl_xor(ss, 1);
    if (shalf == 0) xn2[srow] = ss;
    __syncthreads();

    // ---- epilogue: lane holds panel-row = pt*128+64wp+16pf+(4l4+j), x-row = 64wx+16xf+l15
    // pf = 2K+typ: typ0=w-dot, typ1=beta-dot, k = (pt*4+2wp+K)*16 + 4l4+j  (lane-local pairs)
    const int kb0 = (pt * 4 + 2 * wp) * 16 + 4 * l4;
    f32x4 wn2[2], g2[2], hv[2], alv[2], s2v[2];
#pragma unroll
    for (int K = 0; K < 2; K++) {
        const int kk = kb0 + 16 * K;
        wn2[K] = *(const f32x4*)(prm + kk);
        g2[K]  = *(const f32x4*)(prm + 256 + kk);
        hv[K]  = *(const f32x4*)(prm + 512 + kk);
        alv[K] = *(const f32x4*)(prm + 768 + kk);
        s2v[K] = *(const f32x4*)(prm + 1024 + kk);
    }
    float (*part)[128][3] = (float (*)[128][3])(&Xs[0]);
#pragma unroll
    for (int xf = 0; xf < 4; xf++) {
        const int xrow = 64 * wx + 16 * xf + l15;
        const float xv = xn2[xrow];
        float hs = 0.f, ms = 0.f, gs = 0.f;
#pragma unroll
        for (int K = 0; K < 2; K++) {
#pragma unroll
            for (int j = 0; j < 4; j++) {
                const float aw = acc[2 * K][xf][j];
                const float ab = acc[2 * K + 1][xf][j];
                const float d2 = xv - 2.f * aw + wn2[K][j];
                const float a  = __expf(-g2[K][j] * d2);
                const float ah = a * hv[K][j];
                hs += ah;
                ms += (ab + alv[K][j]) * ah;
                gs += s2v[K][j] * ah * ah;
            }
        }
        hs += __shfl_xor(hs, 16); hs += __shfl_xor(hs, 32);
        ms += __shfl_xor(ms, 16); ms += __shfl_xor(ms, 32);
        gs += __shfl_xor(gs, 16); gs += __shfl_xor(gs, 32);
        if (l4 == 0) {
            part[wp][xrow][0] = hs;
            part[wp][xrow][1] = ms;
            part[wp][xrow][2] = gs;
        }
    }
    __syncthreads();
    if (tid < 128) {
        const int gr = xt * 128 + tid;
#pragma unroll
        for (int v = 0; v < 3; v++)
            pwsS[(size_t)(pt * 3 + v) * NT + gr] = part[0][tid][v] + part[1][tid][v];
    }
}

// ---------------- combine: all outputs from 4 pt-partials per source ----------------
__global__ void combine_kernel(const float* __restrict__ pws,
                               const float* __restrict__ d0, const float* __restrict__ d1,
                               const float* __restrict__ d2, float* __restrict__ out) {
    const int t = blockIdx.x * 256 + threadIdx.x;
    float mux[3], s2x[3], hx[3];
#pragma unroll
    for (int s = 0; s < 3; s++) {
        const float* bbase = pws + (size_t)s * 12 * NT;
        float hh = 0.f, mm = 0.f, gg = 0.f;
#pragma unroll
        for (int pt = 0; pt < 4; pt++) {
            hh += bbase[(size_t)(pt * 3 + 0) * NT + t];
            mm += bbase[(size_t)(pt * 3 + 1) * NT + t];
            gg += bbase[(size_t)(pt * 3 + 2) * NT + t];
        }
        mux[s] = mm / hh; s2x[s] = gg / (hh * hh); hx[s] = hh;
        out[(size_t)s * NT + t]       = mux[s];
        out[(size_t)(4 + s) * NT + t] = s2x[s];
        out[(size_t)(8 + s) * NT + t] = hh;
    }
    const float sd0 = 1.f / (1.f + __expf(-d0[0]));
    const float sd1 = 1.f / (1.f + __expf(-d1[0]));
    const float sd2 = 1.f / (1.f + __expf(-d2[0]));
    const float c0 = hx[0] * sd0, c1 = hx[1] * sd1, c2 = hx[2] * sd2;
    const float den = c0 + c1 + c2;
    const float muc = mux[0] * c0 + mux[1] * c1 + mux[2] * c2;
    const float sgc = s2x[0] * c0 * c0 + s2x[1] * c1 * c1 + s2x[2] * c2 * c2;
    out[(size_t)3 * NT + t]  = muc / den;
    out[(size_t)7 * NT + t]  = sgc / (den * den);
    out[(size_t)11 * NT + t] = den;
}

extern "C" void kernel_launch(void* const* d_in, const int* in_sizes, int n_in,
                              void* d_out, int out_size, void* d_ws, size_t ws_size,
                              hipStream_t stream) {
    // input order per source i: x=8i, alpha=8i+1, beta=8i+2, sig=8i+3, eta=8i+4, gam=8i+5, w=8i+6, disc=8i+7
    const float* x0 = (const float*)d_in[0];
    const float* x1 = (const float*)d_in[8];
    const float* x2 = (const float*)d_in[16];

    unsigned short* bc = (unsigned short*)d_ws;                  // 512*(512+256+128) ushorts = 917504 B
    float* prmAll = (float*)((char*)d_ws + 917504);              // 3*1280 floats = 15360 B
    float* pws    = (float*)((char*)d_ws + 917504 + 15360);      // 3*4*3*NT floats = 9.44 MB
    float* out = (float*)d_out;

    prep_kernel<<<1536, 128, 0, stream>>>(
        (const float*)d_in[6],  (const float*)d_in[2],  (const float*)d_in[1],
        (const float*)d_in[3],  (const float*)d_in[4],  (const float*)d_in[5],
        (const float*)d_in[14], (const float*)d_in[10], (const float*)d_in[9],
        (const float*)d_in[11], (const float*)d_in[12], (const float*)d_in[13],
        (const float*)d_in[22], (const float*)d_in[18], (const float*)d_in[17],
        (const float*)d_in[19], (const float*)d_in[20], (const float*)d_in[21],
        bc, prmAll);

    const size_t bcoff1 = 512 * 512, bcoff2 = 512 * 512 + 512 * 256;
    fused_src<512><<<2048, 256, 0, stream>>>(x0, bc,          prmAll,        pws);
    fused_src<256><<<2048, 256, 0, stream>>>(x1, bc + bcoff1, prmAll + 1280, pws + (size_t)12 * NT);
    fused_src<128><<<2048, 256, 0, stream>>>(x2, bc + bcoff2, prmAll + 2560, pws + (size_t)24 * NT);
    combine_kernel<<<256, 256, 0, stream>>>(pws, (const float*)d_in[7], (const float*)d_in[15],
                                            (const float*)d_in[23], out);
}

// Round 8
// 126.055 us; speedup vs baseline: 1.4422x; 1.0341x over previous
//
#include <hip/hip_runtime.h>
#include <hip/hip_bf16.h>

typedef __attribute__((ext_vector_type(8))) short short8;
typedef __attribute__((ext_vector_type(4))) float f32x4;

#define NT 65536

__device__ __forceinline__ unsigned short f2bf(float f) {
    union { float f; unsigned int u; } v; v.f = f;
    unsigned int u = v.u;
    unsigned int r = (u + 0x7fffu + ((u >> 16) & 1u)) >> 16;  // RNE
    return (unsigned short)r;
}

__device__ __forceinline__ unsigned int cvt_pk_bf16(float lo, float hi) {
    unsigned int r;
    asm("v_cvt_pk_bf16_f32 %0, %1, %2" : "=v"(r) : "v"(lo), "v"(hi));
    return r;
}

#define LGKM0()  asm volatile("s_waitcnt lgkmcnt(0)" ::: "memory")
#define BAR()    __builtin_amdgcn_s_barrier()
#define SB0()    __builtin_amdgcn_sched_barrier(0)

// ---------------- prep (all 3 sources): bf16 B panel + per-k params ----------------
// Panel row n: k16=n>>5, typ=(n>>4)&1, r=n&15 -> k=k16*16+r; typ0=w, typ1=beta.
// prm per source (5*256 f32): [0:256)=||w_k||^2, [256)=gam^2, [512)=eta^2, [768)=alpha, [1024)=sig^2
__global__ void prep_kernel(const float* __restrict__ w0, const float* __restrict__ b0,
                            const float* __restrict__ a0, const float* __restrict__ s0,
                            const float* __restrict__ e0, const float* __restrict__ g0,
                            const float* __restrict__ w1, const float* __restrict__ b1,
                            const float* __restrict__ a1, const float* __restrict__ s1,
                            const float* __restrict__ e1, const float* __restrict__ g1,
                            const float* __restrict__ w2, const float* __restrict__ b2,
                            const float* __restrict__ a2, const float* __restrict__ s2,
                            const float* __restrict__ e2, const float* __restrict__ g2,
                            unsigned short* __restrict__ bc, float* __restrict__ prmAll) {
    __shared__ float red[2];
    const int bx = blockIdx.x;
    const int s = bx >> 9;            // 0..2
    const int n = bx & 511;           // panel row
    const int P = 512 >> s;
    const float* w   = (s == 0) ? w0 : ((s == 1) ? w1 : w2);
    const float* bet = (s == 0) ? b0 : ((s == 1) ? b1 : b2);
    const float* alp = (s == 0) ? a0 : ((s == 1) ? a1 : a2);
    const float* sig = (s == 0) ? s0 : ((s == 1) ? s1 : s2);
    const float* eta = (s == 0) ? e0 : ((s == 1) ? e1 : e2);
    const float* gam = (s == 0) ? g0 : ((s == 1) ? g1 : g2);
    unsigned short* dstb = bc + ((s == 0) ? 0 : ((s == 1) ? (512 * 512) : (512 * 512 + 512 * 256)));
    float* prm = prmAll + 1280 * s;

    const int tid = threadIdx.x;      // 128
    const int k16 = n >> 5;
    const int typ = (n >> 4) & 1;
    const int k = k16 * 16 + (n & 15);
    const bool isw = (typ == 0);
    const float* src = (isw ? w : bet) + (size_t)k * P;
    unsigned short* dst = dstb + (size_t)n * P;
    float ss = 0.f;
    for (int c = tid; c < P; c += 128) {
        float f = src[c];
        dst[c] = f2bf(f);
        if (isw) ss += f * f;
    }
#pragma unroll
    for (int m = 1; m < 64; m <<= 1) ss += __shfl_xor(ss, m);
    if ((tid & 63) == 0) red[tid >> 6] = ss;
    __syncthreads();
    if (isw && tid == 0) prm[k] = red[0] + red[1];
    if (n == 0) {
        for (int kk = tid; kk < 256; kk += 128) {
            float g = gam[kk], e = eta[kk];
            prm[256 + kk]  = g * g;
            prm[512 + kk]  = e * e;
            prm[768 + kk]  = alp[kk];
            prm[1024 + kk] = sig[kk] * sig[kk];
        }
    }
}

// ---------------- fused per-source: small-tile streaming GEMM, depth-3 pipeline ----------------
// grid 2048, 256 thr (4 waves 2(panel)x2(x)). Block: 128 panel-rows (pt) x 128 x-rows (xt),
// BK=32, NK=P/32. Grid swizzle: xt=(b>>5)*8+(b&7), pt=(b>>3)&3 -> pt-siblings on one XCD.
// DEPTH-3 PREFETCH: B in 4-deep LDS ring (global_load_lds), x in 4 static reg sets.
// Issue order pinned (gloadB(t+3); SB0; loadX(t+3)) so cvtWrite(t+1)'s register waits,
// via in-order VMEM retirement, also retire gloadB(t+1): ~3 steps (~1800cy) latency cover,
// no explicit vmcnt anywhere. 2 raw barriers/step; LGKM0 before BAR for ds_write visibility.
// Swapped MFMA: mfma(panel_frag, x_frag) -> k lane-local in regs; epilogue = adds + 2 shuffles.
// LDS 16B-slot swizzle: phys = slot ^ ((row>>1)&3) -> conflict-free (verified 0 in R7).
template<int P>
__global__ __launch_bounds__(256, 3)
void fused_src(const float* __restrict__ x, const unsigned short* __restrict__ Bc,
               const float* __restrict__ prm, float* __restrict__ pwsS) {
    constexpr int NK = P / 32;
    __shared__ unsigned short Bs[4][128 * 32];   // 32 KB (4-deep ring)
    __shared__ unsigned short Xs[2][128 * 32];   // 16 KB (dbuf)
    __shared__ float xn2[128];

    const int b = blockIdx.x;
    const int xt = (b >> 5) * 8 + (b & 7);
    const int pt = (b >> 3) & 3;

    const int tid = threadIdx.x, lane = tid & 63, wv = tid >> 6;
    const int wp = wv >> 1, wx = wv & 1;
    const int l15 = lane & 15, l4 = lane >> 4;

    const int srow = tid >> 1, shalf = tid & 1;
    const float* xbase = x + (size_t)(xt * 128 + srow) * P + shalf * 16;

    f32x4 acc[4][4];
#pragma unroll
    for (int pf = 0; pf < 4; pf++)
#pragma unroll
        for (int xf = 0; xf < 4; xf++) acc[pf][xf] = (f32x4){0.f, 0.f, 0.f, 0.f};

    float4 xr[4][4];   // 4 static register sets (full unroll -> all indices static)
    float ss = 0.f;

    auto gloadB = [&](int nb, int t) {
#pragma unroll
        for (int i = 0; i < 2; i++) {
            const int u = i * 256 + tid;
            const int row = u >> 2;
            const int sl = (u & 3) ^ ((row >> 1) & 3);
            const unsigned short* src = Bc + (size_t)(pt * 128 + row) * P + t * 32 + sl * 8;
            __builtin_amdgcn_global_load_lds((const __attribute__((address_space(1))) void*)src,
                (__attribute__((address_space(3))) void*)&Bs[nb][(i * 256 + wv * 64) * 8], 16, 0, 0);
        }
    };
    auto loadX = [&](float4* xrs, int t) {
#pragma unroll
        for (int i = 0; i < 4; i++) xrs[i] = *(const float4*)(xbase + t * 32 + i * 4);
    };
    auto cvtWrite = [&](const float4* xrs, int xb) {
        const int sw = (srow >> 1) & 3;
#pragma unroll
        for (int hh = 0; hh < 2; hh++) {
            float4 q0 = xrs[2 * hh], q1 = xrs[2 * hh + 1];
            ss += q0.x*q0.x + q0.y*q0.y + q0.z*q0.z + q0.w*q0.w
                + q1.x*q1.x + q1.y*q1.y + q1.z*q1.z + q1.w*q1.w;
            uint4 pk = { cvt_pk_bf16(q0.x, q0.y), cvt_pk_bf16(q0.z, q0.w),
                         cvt_pk_bf16(q1.x, q1.y), cvt_pk_bf16(q1.z, q1.w) };
            const int phys = (shalf * 2 + hh) ^ sw;
            *(uint4*)(&Xs[xb][srow * 32 + phys * 8]) = pk;
        }
    };
    auto compute = [&](int bb, int xb) {
        short8 af[4], bf[4];
#pragma unroll
        for (int pf = 0; pf < 4; pf++) {
            const int row = 64 * wp + 16 * pf + l15;
            af[pf] = *(const short8*)(&Bs[bb][row * 32 + ((l4 ^ ((row >> 1) & 3)) << 3)]);
        }
#pragma unroll
        for (int xf = 0; xf < 4; xf++) {
            const int row = 64 * wx + 16 * xf + l15;
            bf[xf] = *(const short8*)(&Xs[xb][row * 32 + ((l4 ^ ((row >> 1) & 3)) << 3)]);
        }
#pragma unroll
        for (int pf = 0; pf < 4; pf++)
#pragma unroll
            for (int xf = 0; xf < 4; xf++)
                acc[pf][xf] = __builtin_amdgcn_mfma_f32_16x16x32_bf16(af[pf], bf[xf], acc[pf][xf], 0, 0, 0);
    };

    // ---- prologue: issue loads for steps 0..2, stage X(0) ----
#pragma unroll
    for (int d = 0; d < 3; d++) {
        if (d < NK) {
            gloadB(d, d); SB0();
            loadX(xr[d], d); SB0();
        }
    }
    cvtWrite(xr[0], 0);      // reg deps retire gloadB(0) too (in-order VMEM)
    LGKM0(); SB0(); BAR(); SB0();

    // ---- main loop (full unroll: every index static) ----
#pragma unroll
    for (int t = 0; t < NK; t++) {
        if (t + 3 < NK) {
            gloadB((t + 3) & 3, t + 3); SB0();
            loadX(xr[(t + 3) & 3], t + 3); SB0();
        }
        if (t + 1 < NK) {
            cvtWrite(xr[(t + 1) & 3], (t + 1) & 1);   // waits retire gloadB(t+1)
        }
        LGKM0(); SB0(); BAR(); SB0();
        compute(t & 3, t & 1);
        SB0(); BAR(); SB0();
    }

    // ---- ||x||^2 finalize (2 threads per row) ----
    ss += __shfl_xor(ss, 1);
    if (shalf == 0) xn2[srow] = ss;
    __syncthreads();

    // ---- epilogue: lane holds panel-row = pt*128+64wp+16pf+(4l4+j), x-row = 64wx+16xf+l15
    // pf = 2K+typ: typ0=w-dot, typ1=beta-dot, k = (pt*4+2wp+K)*16 + 4l4+j (lane-local)
    const int kb0 = (pt * 4 + 2 * wp) * 16 + 4 * l4;
    f32x4 wn2[2], g2[2], hv[2], alv[2], s2v[2];
#pragma unroll
    for (int K = 0; K < 2; K++) {
        const int kk = kb0 + 16 * K;
        wn2[K] = *(const f32x4*)(prm + kk);
        g2[K]  = *(const f32x4*)(prm + 256 + kk);
        hv[K]  = *(const f32x4*)(prm + 512 + kk);
        alv[K] = *(const f32x4*)(prm + 768 + kk);
        s2v[K] = *(const f32x4*)(prm + 1024 + kk);
    }
    float (*part)[128][3] = (float (*)[128][3])(&Bs[0][0]);   // alias dead B ring
#pragma unroll
    for (int xf = 0; xf < 4; xf++) {
        const int xrow = 64 * wx + 16 * xf + l15;
        const float xv = xn2[xrow];
        float hs = 0.f, ms = 0.f, gs = 0.f;
#pragma unroll
        for (int K = 0; K < 2; K++) {
#pragma unroll
            for (int j = 0; j < 4; j++) {
                const float aw = acc[2 * K][xf][j];
                const float ab = acc[2 * K + 1][xf][j];
                const float d2 = xv - 2.f * aw + wn2[K][j];
                const float a  = __expf(-g2[K][j] * d2);
                const float ah = a * hv[K][j];
                hs += ah;
                ms += (ab + alv[K][j]) * ah;
                gs += s2v[K][j] * ah * ah;
            }
        }
        hs += __shfl_xor(hs, 16); hs += __shfl_xor(hs, 32);
        ms += __shfl_xor(ms, 16); ms += __shfl_xor(ms, 32);
        gs += __shfl_xor(gs, 16); gs += __shfl_xor(gs, 32);
        if (l4 == 0) {
            part[wp][xrow][0] = hs;
            part[wp][xrow][1] = ms;
            part[wp][xrow][2] = gs;
        }
    }
    __syncthreads();
    if (tid < 128) {
        const int gr = xt * 128 + tid;
#pragma unroll
        for (int v = 0; v < 3; v++)
            pwsS[(size_t)(pt * 3 + v) * NT + gr] = part[0][tid][v] + part[1][tid][v];
    }
}

// ---------------- combine: all outputs from 4 pt-partials per source ----------------
__global__ void combine_kernel(const float* __restrict__ pws,
                               const float* __restrict__ d0, const float* __restrict__ d1,
                               const float* __restrict__ d2, float* __restrict__ out) {
    const int t = blockIdx.x * 256 + threadIdx.x;
    float mux[3], s2x[3], hx[3];
#pragma unroll
    for (int s = 0; s < 3; s++) {
        const float* bbase = pws + (size_t)s * 12 * NT;
        float hh = 0.f, mm = 0.f, gg = 0.f;
#pragma unroll
        for (int pt = 0; pt < 4; pt++) {
            hh += bbase[(size_t)(pt * 3 + 0) * NT + t];
            mm += bbase[(size_t)(pt * 3 + 1) * NT + t];
            gg += bbase[(size_t)(pt * 3 + 2) * NT + t];
        }
        mux[s] = mm / hh; s2x[s] = gg / (hh * hh); hx[s] = hh;
        out[(size_t)s * NT + t]       = mux[s];
        out[(size_t)(4 + s) * NT + t] = s2x[s];
        out[(size_t)(8 + s) * NT + t] = hh;
    }
    const float sd0 = 1.f / (1.f + __expf(-d0[0]));
    const float sd1 = 1.f / (1.f + __expf(-d1[0]));
    const float sd2 = 1.f / (1.f + __expf(-d2[0]));
    const float c0 = hx[0] * sd0, c1 = hx[1] * sd1, c2 = hx[2] * sd2;
    const float den = c0 + c1 + c2;
    const float muc = mux[0] * c0 + mux[1] * c1 + mux[2] * c2;
    const float sgc = s2x[0] * c0 * c0 + s2x[1] * c1 * c1 + s2x[2] * c2 * c2;
    out[(size_t)3 * NT + t]  = muc / den;
    out[(size_t)7 * NT + t]  = sgc / (den * den);
    out[(size_t)11 * NT + t] = den;
}

extern "C" void kernel_launch(void* const* d_in, const int* in_sizes, int n_in,
                              void* d_out, int out_size, void* d_ws, size_t ws_size,
                              hipStream_t stream) {
    // input order per source i: x=8i, alpha=8i+1, beta=8i+2, sig=8i+3, eta=8i+4, gam=8i+5, w=8i+6, disc=8i+7
    const float* x0 = (const float*)d_in[0];
    const float* x1 = (const float*)d_in[8];
    const float* x2 = (const float*)d_in[16];

    unsigned short* bc = (unsigned short*)d_ws;                  // 512*(512+256+128) ushorts = 917504 B
    float* prmAll = (float*)((char*)d_ws + 917504);              // 3*1280 floats = 15360 B
    float* pws    = (float*)((char*)d_ws + 917504 + 15360);      // 3*4*3*NT floats = 9.44 MB
    float* out = (float*)d_out;

    prep_kernel<<<1536, 128, 0, stream>>>(
        (const float*)d_in[6],  (const float*)d_in[2],  (const float*)d_in[1],
        (const float*)d_in[3],  (const float*)d_in[4],  (const float*)d_in[5],
        (const float*)d_in[14], (const float*)d_in[10], (const float*)d_in[9],
        (const float*)d_in[11], (const float*)d_in[12], (const float*)d_in[13],
        (const float*)d_in[22], (const float*)d_in[18], (const float*)d_in[17],
        (const float*)d_in[19], (const float*)d_in[20], (const float*)d_in[21],
        bc, prmAll);

    const size_t bcoff1 = 512 * 512, bcoff2 = 512 * 512 + 512 * 256;
    fused_src<512><<<2048, 256, 0, stream>>>(x0, bc,          prmAll,        pws);
    fused_src<256><<<2048, 256, 0, stream>>>(x1, bc + bcoff1, prmAll + 1280, pws + (size_t)12 * NT);
    fused_src<128><<<2048, 256, 0, stream>>>(x2, bc + bcoff2, prmAll + 2560, pws + (size_t)24 * NT);
    combine_kernel<<<256, 256, 0, stream>>>(pws, (const float*)d_in[7], (const float*)d_in[15],
                                            (const float*)d_in[23], out);
}